// Round 2
// baseline (331.803 us; speedup 1.0000x reference)
//
#include <hip/hip_runtime.h>

// GuidedAttentionLoss: out = sum_{b, i<To[b], j<Ti[b]} A[b,i,j] * (1 - exp(-(i - j*To/Ti)^2 / (2*sigma^2))) / B
// A: [B, T_out, T_in] fp32, T_in = 512. HBM-bound streaming reduction.
//
// R4: single-variable A/B vs R3 — drop __builtin_nontemporal_load, use plain
// cached vector loads. Theory: NT reads bypass the L2/L3 request-aggregation
// path and cap streaming read BW at ~1.3 TB/s (both prior kernels flat at
// ~155 us kernel-residual while the plain-write fillBuffer streams 6.6 TB/s).
// Everything else identical to R3: 2D grid (chunk, b) with block-uniform
// scalar lengths, countable row loop (i<To folded into trip count), 2-row
// software pipeline, j>=Ti vector-granular load skip.

#define GAL_SIGMA  0.4f
#define GAL_TIN    512
#define GAL_CHUNKS 32

typedef float vfloat4 __attribute__((ext_vector_type(4)));

__global__ __launch_bounds__(256) void gal_main_kernel(
    const float* __restrict__ align,
    const int*   __restrict__ in_len,
    const int*   __restrict__ out_len,
    float*       __restrict__ partials,
    int T_out)
{
    const int lane    = threadIdx.x & 63;
    const int wid     = threadIdx.x >> 6;
    const int b       = blockIdx.y;        // uniform -> scalar registers
    const int nchunks = gridDim.x;

    const int   Ti    = in_len[b];         // scalar load (b is block-uniform)
    const int   To    = out_len[b];
    const float ratio = (float)To / (float)Ti;
    const float cexp  = -1.0f / (2.0f * GAL_SIGMA * GAL_SIGMA);

    const int chunk_len = (T_out + nchunks - 1) / nchunks;
    const int i_begin   = blockIdx.x * chunk_len;
    int i_end = i_begin + chunk_len;
    if (i_end > T_out) i_end = T_out;
    if (i_end > To)    i_end = To;         // rows i >= To are zero-weight: never loaded

    float acc = 0.0f;

    const int i0 = i_begin + wid;          // wave-private row start, stride 4 rows
    if (i0 < i_end) {
        const int nk = (i_end - i0 + 3) >> 2;   // countable trip count -> pipelineable

        const int ja = lane << 2;               // j in [0,256)
        const int jb = 256 + (lane << 2);       // j in [256,512)

        // Hoisted per-lane constants: diagonal targets and validity masks.
        float jra[4], jrb[4];
        bool  mva[4], mvb[4];
        #pragma unroll
        for (int e = 0; e < 4; ++e) {
            jra[e] = (float)(ja + e) * ratio;
            jrb[e] = (float)(jb + e) * ratio;
            mva[e] = (ja + e) < Ti;
            mvb[e] = (jb + e) < Ti;
        }
        const bool v0 = ja < Ti;    // vector-granular load guards (Ti >= 256 in practice)
        const bool v1 = jb < Ti;

        const vfloat4* p = (const vfloat4*)(align + (size_t)(b * T_out + i0) * GAL_TIN);

        // Prologue: current row's two halves (plain cached loads).
        vfloat4 a0 = {0.f, 0.f, 0.f, 0.f}, a1 = {0.f, 0.f, 0.f, 0.f};
        if (v0) a0 = p[lane];
        if (v1) a1 = p[64 + lane];

        float fi = (float)i0;
        for (int k = 0; k < nk; ++k) {
            // Issue next row's loads before computing current (2-deep pipeline).
            vfloat4 n0 = {0.f, 0.f, 0.f, 0.f}, n1 = {0.f, 0.f, 0.f, 0.f};
            if (k + 1 < nk) {
                const vfloat4* pn = p + (size_t)(k + 1) * (4 * (GAL_TIN / 4));
                if (v0) n0 = pn[lane];
                if (v1) n1 = pn[64 + lane];
            }

            #pragma unroll
            for (int e = 0; e < 4; ++e) {
                const float d = fi - jra[e];
                const float w = 1.0f - __expf(d * d * cexp);
                acc += mva[e] ? a0[e] * w : 0.0f;
            }
            #pragma unroll
            for (int e = 0; e < 4; ++e) {
                const float d = fi - jrb[e];
                const float w = 1.0f - __expf(d * d * cexp);
                acc += mvb[e] ? a1[e] * w : 0.0f;
            }

            a0 = n0; a1 = n1;
            fi += 4.0f;
        }
    }

    // wave reduce (64 lanes)
    #pragma unroll
    for (int off = 32; off > 0; off >>= 1)
        acc += __shfl_down(acc, off, 64);

    __shared__ float smem[4];
    if (lane == 0) smem[wid] = acc;
    __syncthreads();
    if (threadIdx.x == 0)
        partials[blockIdx.y * nchunks + blockIdx.x] = smem[0] + smem[1] + smem[2] + smem[3];
}

__global__ __launch_bounds__(256) void gal_reduce_kernel(
    const float* __restrict__ partials,
    float*       __restrict__ out,
    int n, float inv_B)
{
    float acc = 0.0f;
    for (int idx = threadIdx.x; idx < n; idx += 256)
        acc += partials[idx];

    #pragma unroll
    for (int off = 32; off > 0; off >>= 1)
        acc += __shfl_down(acc, off, 64);

    __shared__ float smem[4];
    const int lane = threadIdx.x & 63;
    const int wid  = threadIdx.x >> 6;
    if (lane == 0) smem[wid] = acc;
    __syncthreads();
    if (threadIdx.x == 0)
        out[0] = (smem[0] + smem[1] + smem[2] + smem[3]) * inv_B;
}

extern "C" void kernel_launch(void* const* d_in, const int* in_sizes, int n_in,
                              void* d_out, int out_size, void* d_ws, size_t ws_size,
                              hipStream_t stream) {
    const float* align   = (const float*)d_in[0];
    const int*   in_len  = (const int*)d_in[1];   // input_lengths  [B]
    const int*   out_len = (const int*)d_in[2];   // output_lengths [B]
    float* out      = (float*)d_out;
    float* partials = (float*)d_ws;

    const int B     = in_sizes[1];
    const int T_out = in_sizes[0] / (B * GAL_TIN);

    int chunks = GAL_CHUNKS;
    const int max_parts = (int)(ws_size / sizeof(float));
    while (chunks > 1 && chunks * B > max_parts) chunks >>= 1;   // safety only

    gal_main_kernel<<<dim3(chunks, B), 256, 0, stream>>>(align, in_len, out_len,
                                                         partials, T_out);
    gal_reduce_kernel<<<1, 256, 0, stream>>>(partials, out, chunks * B,
                                             1.0f / (float)B);
}

// Round 3
// 316.507 us; speedup vs baseline: 1.0483x; 1.0483x over previous
//
#include <hip/hip_runtime.h>

// GuidedAttentionLoss: out = sum_{b, i<To[b], j<Ti[b]} A[b,i,j] * (1 - exp(-(i - j*To/Ti)^2 / (2*sigma^2))) / B
// A: [B, T_out, T_in] fp32, T_in = 512. HBM-bound streaming reduction.
//
// R5: revert R4's cached loads back to __builtin_nontemporal_load (A/B/A).
// Timing decomposition across R0-R2 shows dur_us == 2 x (1 GiB workspace
// poison fill) + kernel marginal: NT variants = -0.1/-5.7 us marginal,
// cached variant = +15.9 us. NT reads skip L2/L3 allocation so the 262 MB
// streamed input doesn't contend with the harness's 2 GiB of poison-fill
// traffic; cached reads do. Structure otherwise identical to R3: 2D grid
// (chunk, b) with block-uniform scalar lengths, countable row loop (i<To
// folded into trip count), 2-row software pipeline, per-lane exec-masked
// load skip for j >= Ti.

#define GAL_SIGMA  0.4f
#define GAL_TIN    512
#define GAL_CHUNKS 32

typedef float vfloat4 __attribute__((ext_vector_type(4)));

__global__ __launch_bounds__(256) void gal_main_kernel(
    const float* __restrict__ align,
    const int*   __restrict__ in_len,
    const int*   __restrict__ out_len,
    float*       __restrict__ partials,
    int T_out)
{
    const int lane    = threadIdx.x & 63;
    const int wid     = threadIdx.x >> 6;
    const int b       = blockIdx.y;        // uniform -> scalar registers
    const int nchunks = gridDim.x;

    const int   Ti    = in_len[b];         // scalar load (b is block-uniform)
    const int   To    = out_len[b];
    const float ratio = (float)To / (float)Ti;
    const float cexp  = -1.0f / (2.0f * GAL_SIGMA * GAL_SIGMA);

    const int chunk_len = (T_out + nchunks - 1) / nchunks;
    const int i_begin   = blockIdx.x * chunk_len;
    int i_end = i_begin + chunk_len;
    if (i_end > T_out) i_end = T_out;
    if (i_end > To)    i_end = To;         // rows i >= To are zero-weight: never loaded

    float acc = 0.0f;

    const int i0 = i_begin + wid;          // wave-private row start, stride 4 rows
    if (i0 < i_end) {
        const int nk = (i_end - i0 + 3) >> 2;   // countable trip count -> pipelineable

        const int ja = lane << 2;               // j in [0,256)
        const int jb = 256 + (lane << 2);       // j in [256,512)

        // Hoisted per-lane constants: diagonal targets and validity masks.
        float jra[4], jrb[4];
        bool  mva[4], mvb[4];
        #pragma unroll
        for (int e = 0; e < 4; ++e) {
            jra[e] = (float)(ja + e) * ratio;
            jrb[e] = (float)(jb + e) * ratio;
            mva[e] = (ja + e) < Ti;
            mvb[e] = (jb + e) < Ti;
        }
        const bool v0 = ja < Ti;    // vector-granular load guards (Ti >= 256 in practice)
        const bool v1 = jb < Ti;

        const vfloat4* p = (const vfloat4*)(align + (size_t)(b * T_out + i0) * GAL_TIN);

        // Prologue: current row's two halves (nontemporal: no L2/L3 allocate).
        vfloat4 a0 = {0.f, 0.f, 0.f, 0.f}, a1 = {0.f, 0.f, 0.f, 0.f};
        if (v0) a0 = __builtin_nontemporal_load(p + lane);
        if (v1) a1 = __builtin_nontemporal_load(p + 64 + lane);

        float fi = (float)i0;
        for (int k = 0; k < nk; ++k) {
            // Issue next row's loads before computing current (2-deep pipeline).
            vfloat4 n0 = {0.f, 0.f, 0.f, 0.f}, n1 = {0.f, 0.f, 0.f, 0.f};
            if (k + 1 < nk) {
                const vfloat4* pn = p + (size_t)(k + 1) * (4 * (GAL_TIN / 4));
                if (v0) n0 = __builtin_nontemporal_load(pn + lane);
                if (v1) n1 = __builtin_nontemporal_load(pn + 64 + lane);
            }

            #pragma unroll
            for (int e = 0; e < 4; ++e) {
                const float d = fi - jra[e];
                const float w = 1.0f - __expf(d * d * cexp);
                acc += mva[e] ? a0[e] * w : 0.0f;
            }
            #pragma unroll
            for (int e = 0; e < 4; ++e) {
                const float d = fi - jrb[e];
                const float w = 1.0f - __expf(d * d * cexp);
                acc += mvb[e] ? a1[e] * w : 0.0f;
            }

            a0 = n0; a1 = n1;
            fi += 4.0f;
        }
    }

    // wave reduce (64 lanes)
    #pragma unroll
    for (int off = 32; off > 0; off >>= 1)
        acc += __shfl_down(acc, off, 64);

    __shared__ float smem[4];
    if (lane == 0) smem[wid] = acc;
    __syncthreads();
    if (threadIdx.x == 0)
        partials[blockIdx.y * nchunks + blockIdx.x] = smem[0] + smem[1] + smem[2] + smem[3];
}

__global__ __launch_bounds__(256) void gal_reduce_kernel(
    const float* __restrict__ partials,
    float*       __restrict__ out,
    int n, float inv_B)
{
    float acc = 0.0f;
    for (int idx = threadIdx.x; idx < n; idx += 256)
        acc += partials[idx];

    #pragma unroll
    for (int off = 32; off > 0; off >>= 1)
        acc += __shfl_down(acc, off, 64);

    __shared__ float smem[4];
    const int lane = threadIdx.x & 63;
    const int wid  = threadIdx.x >> 6;
    if (lane == 0) smem[wid] = acc;
    __syncthreads();
    if (threadIdx.x == 0)
        out[0] = (smem[0] + smem[1] + smem[2] + smem[3]) * inv_B;
}

extern "C" void kernel_launch(void* const* d_in, const int* in_sizes, int n_in,
                              void* d_out, int out_size, void* d_ws, size_t ws_size,
                              hipStream_t stream) {
    const float* align   = (const float*)d_in[0];
    const int*   in_len  = (const int*)d_in[1];   // input_lengths  [B]
    const int*   out_len = (const int*)d_in[2];   // output_lengths [B]
    float* out      = (float*)d_out;
    float* partials = (float*)d_ws;

    const int B     = in_sizes[1];
    const int T_out = in_sizes[0] / (B * GAL_TIN);

    int chunks = GAL_CHUNKS;
    const int max_parts = (int)(ws_size / sizeof(float));
    while (chunks > 1 && chunks * B > max_parts) chunks >>= 1;   // safety only

    gal_main_kernel<<<dim3(chunks, B), 256, 0, stream>>>(align, in_len, out_len,
                                                         partials, T_out);
    gal_reduce_kernel<<<1, 256, 0, stream>>>(partials, out, chunks * B,
                                             1.0f / (float)B);
}